// Round 1
// baseline (949.441 us; speedup 1.0000x reference)
//
#include <hip/hip_runtime.h>
#include <math.h>

#define DEV_EPS 1e-5f

namespace {
constexpr int B_ = 16, C_ = 256, H_ = 56, W_ = 56, HW_ = H_ * W_;
constexpr int G_ = 16, GC_ = 16, RED_ = 64;

// ---------------------------------------------------------------------------
// Fused GEMM + BatchNorm + activation (+ optional skip-add).
// Out[b](M x N) = act( alpha[m] * (A(MxK) @ X[b](K x N)) + beta[m] ) [+ skip]
//   alpha[m] = g[m]/sqrt(v[m]+eps);  beta[m] = alpha*bias + bb - bm*alpha
// ACT: 0 = tanh, 1 = relu, 2 = none + skip add
// 64x64 output tile per block, K-chunks of 16, 256 threads, 4x4 microtile.
// ---------------------------------------------------------------------------
template <int ACT>
__global__ __launch_bounds__(256)
void gemm_bn(const float* __restrict__ A, const float* __restrict__ X,
             const float* __restrict__ bias,
             const float* __restrict__ bng, const float* __restrict__ bnb,
             const float* __restrict__ bnm, const float* __restrict__ bnv,
             const float* __restrict__ skip, float* __restrict__ out,
             int M, int N, int Kd) {
  __shared__ float As[16][68];
  __shared__ float Bs[16][68];
  __shared__ float aS[64], bS[64];

  const int bz = blockIdx.z;
  const int m0 = blockIdx.y * 64, n0 = blockIdx.x * 64;
  const int tid = threadIdx.x;

  if (tid < 64) {
    int m = m0 + tid;
    float sc = bng[m] * rsqrtf(bnv[m] + DEV_EPS);
    aS[tid] = sc;
    bS[tid] = sc * bias[m] + bnb[m] - bnm[m] * sc;
  }

  const float* Xb = X + (size_t)bz * Kd * N;
  const int ty = tid >> 4, tx = tid & 15;
  const int arow = tid >> 2, ak4 = (tid & 3) << 2;
  const int bk = tid >> 4, bn4 = (tid & 15) << 2;

  float acc[4][4] = {};

  for (int k0 = 0; k0 < Kd; k0 += 16) {
    float4 av = *(const float4*)(A + (size_t)(m0 + arow) * Kd + k0 + ak4);
    float4 xv = *(const float4*)(Xb + (size_t)(k0 + bk) * N + n0 + bn4);
    As[ak4 + 0][arow] = av.x;
    As[ak4 + 1][arow] = av.y;
    As[ak4 + 2][arow] = av.z;
    As[ak4 + 3][arow] = av.w;
    *(float4*)&Bs[bk][bn4] = xv;
    __syncthreads();
#pragma unroll
    for (int kk = 0; kk < 16; kk++) {
      float4 a4 = *(const float4*)&As[kk][ty * 4];
      float4 b4 = *(const float4*)&Bs[kk][tx * 4];
      float ar[4] = {a4.x, a4.y, a4.z, a4.w};
      float br[4] = {b4.x, b4.y, b4.z, b4.w};
#pragma unroll
      for (int i = 0; i < 4; i++)
#pragma unroll
        for (int j = 0; j < 4; j++) acc[i][j] += ar[i] * br[j];
    }
    __syncthreads();
  }

#pragma unroll
  for (int i = 0; i < 4; i++) {
    int m = m0 + ty * 4 + i;
    float al = aS[ty * 4 + i], be = bS[ty * 4 + i];
    float vv[4];
#pragma unroll
    for (int j = 0; j < 4; j++) {
      float t = al * acc[i][j] + be;
      if (ACT == 0) t = tanhf(t);
      if (ACT == 1) t = fmaxf(t, 0.f);
      vv[j] = t;
    }
    size_t off = (size_t)bz * M * N + (size_t)m * N + n0 + tx * 4;
    if (ACT == 2) {
      float4 s4 = *(const float4*)(skip + off);
      vv[0] += s4.x; vv[1] += s4.y; vv[2] += s4.z; vv[3] += s4.w;
    }
    *(float4*)(out + off) = make_float4(vv[0], vv[1], vv[2], vv[3]);
  }
}

// ---------------------------------------------------------------------------
// Fused involution: span-conv (dynamic kernels) + 7x7 gather + BN2 + tanh.
// Block = one (batch b, group g, 2-row x 56-col pixel tile).  K=7, PAD=3.
// Phase A: wts[tap][p] = span_b[g*49+tap] + sum_c span_w[g*49+tap][c]*r[c][p]
// Phase B: t[c=g*16+gc][p] = tanh(a2*sum_{di,dj} wts[di*7+dj][p]*ypatch + b2)
// LDS: region [rs | sws | sbs] (phase A) aliased by ypatch (phase B); wts and
// bn2 params live outside the aliased region.
// ---------------------------------------------------------------------------
constexpr int RS_STR = 116;     // r tile stride (112 pixels, padded, %4==0)
constexpr int PATCH_STR = 520;  // per-gc y-patch plane: 8 rows * 64 + 8 pad
constexpr int OFF_RS = 0;                 // 64 * 116 = 7424 floats
constexpr int OFF_SWS = 7424;             // 49 * 64  = 3136 floats
constexpr int OFF_SBS = 10560;            // 49 floats
constexpr int OFF_WTS = 10624;            // 49 * 112 = 5488 floats
constexpr int OFF_A2 = 16112;             // 16
constexpr int OFF_B2 = 16128;             // 16
constexpr int SMEM_TOTAL = 16144;         // floats (63.1 KB)

__global__ __launch_bounds__(256)
void inv_fused(const float* __restrict__ y, const float* __restrict__ r,
               const float* __restrict__ span_w, const float* __restrict__ span_b,
               const float* __restrict__ g2, const float* __restrict__ b2,
               const float* __restrict__ m2, const float* __restrict__ v2,
               float* __restrict__ tout) {
  __shared__ float smem[SMEM_TOTAL];
  float* rs = smem + OFF_RS;
  float* sws = smem + OFF_SWS;
  float* sbs = smem + OFF_SBS;
  float* wts = smem + OFF_WTS;
  float* patch = smem;  // aliases rs+sws after phase A
  float* a2s = smem + OFF_A2;
  float* b2s = smem + OFF_B2;

  const int tid = threadIdx.x;
  const int rt = blockIdx.x;  // row tile 0..27
  const int g = blockIdx.y;   // group 0..15
  const int b = blockIdx.z;   // batch 0..15
  const int h0 = rt * 2;
  const int pix0 = h0 * W_;

  // ---- stage r tile, span_w slice, span_b, bn2 params ----
  {
    const float* rb = r + (size_t)b * RED_ * HW_ + pix0;
    for (int idx = tid; idx < RED_ * 112; idx += 256) {
      int c = idx / 112, p = idx - c * 112;
      rs[c * RS_STR + p] = rb[(size_t)c * HW_ + p];
    }
    const float* swg = span_w + (size_t)g * 49 * RED_;
    for (int idx = tid; idx < 49 * RED_; idx += 256) sws[idx] = swg[idx];
    if (tid < 49) sbs[tid] = span_b[g * 49 + tid];
    if (tid < 16) {
      int c = g * GC_ + tid;
      float sc = g2[c] * rsqrtf(v2[c] + DEV_EPS);
      a2s[tid] = sc;
      b2s[tid] = b2[c] - m2[c] * sc;
    }
  }
  __syncthreads();

  // ---- phase A: dynamic weights (49 taps x 112 pixels), 7 taps x 4 px/thread
  if (tid < 196) {
    const int tg = tid / 28, p4 = tid - tg * 28;
    float acc[7][4] = {};
    for (int k = 0; k < RED_; k++) {
      float4 rv = *(const float4*)&rs[k * RS_STR + p4 * 4];
#pragma unroll
      for (int t = 0; t < 7; t++) {
        float sw = sws[(tg * 7 + t) * RED_ + k];
        acc[t][0] += sw * rv.x;
        acc[t][1] += sw * rv.y;
        acc[t][2] += sw * rv.z;
        acc[t][3] += sw * rv.w;
      }
    }
#pragma unroll
    for (int t = 0; t < 7; t++) {
      int tap = tg * 7 + t;
      float sb = sbs[tap];
      *(float4*)&wts[tap * 112 + p4 * 4] =
          make_float4(acc[t][0] + sb, acc[t][1] + sb, acc[t][2] + sb, acc[t][3] + sb);
    }
  }
  __syncthreads();  // wts complete; rs/sws region now dead

  // ---- stage y patch: 16 gc-planes of 8 rows x 62 cols (zero-padded) ----
  {
    const float* yb = y + ((size_t)b * C_ + g * GC_) * HW_;
    for (int idx = tid; idx < GC_ * 8 * 62; idx += 256) {
      int cc = idx / 496;
      int rem = idx - cc * 496;
      int rr = rem / 62;
      int cw = rem - rr * 62;
      int sr = h0 + rr - 3;
      int sc = cw - 3;
      float val = 0.f;
      if (sr >= 0 && sr < H_ && sc >= 0 && sc < W_)
        val = yb[(size_t)cc * HW_ + sr * W_ + sc];
      patch[cc * PATCH_STR + rr * 64 + cw] = val;
    }
  }
  __syncthreads();

  // ---- phase B: 7x7 gather, 2 gc-planes x 4 px per thread ----
  if (tid < 224) {
    const int p4 = tid % 28, gp = tid / 28;  // gp 0..7
    const int pr = p4 / 14, pc0 = (p4 % 14) * 4;
    const int gc0 = gp * 2;
    float acc0[4] = {}, acc1[4] = {};
#pragma unroll
    for (int di = 0; di < 7; di++) {
      int ro0 = gc0 * PATCH_STR + (pr + di) * 64 + pc0;
      int ro1 = ro0 + PATCH_STR;
      float w0[10], w1[10];
      *(float4*)&w0[0] = *(const float4*)&patch[ro0];
      *(float4*)&w0[4] = *(const float4*)&patch[ro0 + 4];
      *(float2*)&w0[8] = *(const float2*)&patch[ro0 + 8];
      *(float4*)&w1[0] = *(const float4*)&patch[ro1];
      *(float4*)&w1[4] = *(const float4*)&patch[ro1 + 4];
      *(float2*)&w1[8] = *(const float2*)&patch[ro1 + 8];
#pragma unroll
      for (int dj = 0; dj < 7; dj++) {
        float4 wt = *(const float4*)&wts[(di * 7 + dj) * 112 + p4 * 4];
        float wtr[4] = {wt.x, wt.y, wt.z, wt.w};
#pragma unroll
        for (int px = 0; px < 4; px++) {
          acc0[px] += wtr[px] * w0[dj + px];
          acc1[px] += wtr[px] * w1[dj + px];
        }
      }
    }
    const int gpix = pix0 + pr * W_ + pc0;
    {
      int c0 = g * GC_ + gc0;
      float al = a2s[gc0], be = b2s[gc0];
      float4 o0 = make_float4(tanhf(al * acc0[0] + be), tanhf(al * acc0[1] + be),
                              tanhf(al * acc0[2] + be), tanhf(al * acc0[3] + be));
      *(float4*)(tout + ((size_t)b * C_ + c0) * HW_ + gpix) = o0;
      al = a2s[gc0 + 1];
      be = b2s[gc0 + 1];
      float4 o1 = make_float4(tanhf(al * acc1[0] + be), tanhf(al * acc1[1] + be),
                              tanhf(al * acc1[2] + be), tanhf(al * acc1[3] + be));
      *(float4*)(tout + ((size_t)b * C_ + c0 + 1) * HW_ + gpix) = o1;
    }
  }
}

}  // namespace

extern "C" void kernel_launch(void* const* d_in, const int* in_sizes, int n_in,
                              void* d_out, int out_size, void* d_ws, size_t ws_size,
                              hipStream_t stream) {
  const float* x = (const float*)d_in[0];
  const float* w1 = (const float*)d_in[1];
  const float* b1 = (const float*)d_in[2];
  const float* bn1g = (const float*)d_in[3];
  const float* bn1b = (const float*)d_in[4];
  const float* bn1m = (const float*)d_in[5];
  const float* bn1v = (const float*)d_in[6];
  const float* red_w = (const float*)d_in[7];
  const float* red_b = (const float*)d_in[8];
  const float* rbg = (const float*)d_in[9];
  const float* rbb = (const float*)d_in[10];
  const float* rbm = (const float*)d_in[11];
  const float* rbv = (const float*)d_in[12];
  const float* span_w = (const float*)d_in[13];
  const float* span_b = (const float*)d_in[14];
  const float* bn2g = (const float*)d_in[15];
  const float* bn2b = (const float*)d_in[16];
  const float* bn2m = (const float*)d_in[17];
  const float* bn2v = (const float*)d_in[18];
  const float* w3 = (const float*)d_in[19];
  const float* b3 = (const float*)d_in[20];
  const float* bn3g = (const float*)d_in[21];
  const float* bn3b = (const float*)d_in[22];
  const float* bn3m = (const float*)d_in[23];
  const float* bn3v = (const float*)d_in[24];

  float* ws = (float*)d_ws;
  float* y = ws;                                  // (B,256,3136)
  float* r = y + (size_t)B_ * C_ * HW_;           // (B,64,3136)
  float* t = r + (size_t)B_ * RED_ * HW_;         // (B,256,3136)
  float* out = (float*)d_out;

  dim3 blk(256);
  // y = tanh(bn1(w1 @ x + b1))
  gemm_bn<0><<<dim3(49, 4, 16), blk, 0, stream>>>(
      w1, x, b1, bn1g, bn1b, bn1m, bn1v, nullptr, y, C_, HW_, C_);
  // r = relu(bn_red(red_w @ y + red_b))
  gemm_bn<1><<<dim3(49, 1, 16), blk, 0, stream>>>(
      red_w, y, red_b, rbg, rbb, rbm, rbv, nullptr, r, RED_, HW_, C_);
  // t = tanh(bn2(involution(y; span(r))))
  inv_fused<<<dim3(28, 16, 16), blk, 0, stream>>>(
      y, r, span_w, span_b, bn2g, bn2b, bn2m, bn2v, t);
  // out = bn3(w3 @ t + b3) + x
  gemm_bn<2><<<dim3(49, 4, 16), blk, 0, stream>>>(
      w3, t, b3, bn3g, bn3b, bn3m, bn3v, x, out, C_, HW_, C_);
}